// Round 15
// baseline (232.544 us; speedup 1.0000x reference)
//
#include <hip/hip_runtime.h>
#include <hip/hip_bf16.h>
#include <math.h>

#define N_NODES 204800
#define B_GRAPHS 4096
#define DIM 128

typedef __attribute__((ext_vector_type(8))) short bf16x8;
typedef __attribute__((ext_vector_type(4))) float f32x4;

__device__ __forceinline__ float sigf(float x) {
    return 1.0f / (1.0f + __expf(-x));
}

__device__ __forceinline__ unsigned short bfrne(float x) {
    unsigned u = __float_as_uint(x);
    unsigned r = u + 0x7FFFu + ((u >> 16) & 1u);
    return (unsigned short)(r >> 16);
}

// ---------------------------------------------------------------------------
// Kernel 1, three jobs by blockIdx.x:
//   [0..512):    q[b] = U_feat[b]@W_user + b_user + feat[last[b]]@W_last
//   [512..576):  Wt_bf16[c][k] = bf16(W_key[k][c])
//   [576..2176): bounds scatter (segments sorted & contiguous)
// ---------------------------------------------------------------------------
__global__ __launch_bounds__(128) void qkernel(
    const float* __restrict__ feat, const float* __restrict__ U_feat,
    const float* __restrict__ W_user, const float* __restrict__ b_user,
    const float* __restrict__ W_last, const int* __restrict__ last_nodes,
    const float* __restrict__ W_key, unsigned short* __restrict__ Wt,
    const int* __restrict__ seg, int* __restrict__ bounds,
    float* __restrict__ q) {
  if (blockIdx.x >= 576) {
    int n = (blockIdx.x - 576) * 128 + threadIdx.x;
    int sc = seg[n];
    int sp = (n == 0) ? -1 : seg[n - 1];
    for (int b = sp + 1; b <= sc; ++b) bounds[b] = (b == 0) ? 0 : n;
    if (n == N_NODES - 1)
      for (int b = sc + 1; b <= B_GRAPHS; ++b) bounds[b] = N_NODES;
    return;
  }
  if (blockIdx.x >= 512) {
    int b = blockIdx.x - 512;  // 0..63
#pragma unroll
    for (int j = 0; j < 2; ++j) {
      int o = b * 256 + j * 128 + threadIdx.x;
      int c = o >> 7, k = o & 127;
      Wt[o] = bfrne(W_key[k * DIM + c]);
    }
    return;
  }
  __shared__ float sU[8][DIM];
  __shared__ float sL[8][DIM];
  const int d = threadIdx.x;
  const int g0 = blockIdx.x * 8;
  for (int g = 0; g < 8; ++g) {
    sU[g][d] = U_feat[(g0 + g) * DIM + d];
    int ln = last_nodes[g0 + g];
    sL[g][d] = feat[ln * DIM + d];
  }
  __syncthreads();
  float acc[8];
#pragma unroll
  for (int g = 0; g < 8; ++g) acc[g] = 0.0f;
  for (int kk = 0; kk < 32; ++kk) {
    float wu[4], wl[4];
#pragma unroll
    for (int j = 0; j < 4; ++j) {
      wu[j] = W_user[(kk * 4 + j) * DIM + d];
      wl[j] = W_last[(kk * 4 + j) * DIM + d];
    }
#pragma unroll
    for (int g = 0; g < 8; ++g) {
      float4 u4 = reinterpret_cast<const float4*>(sU[g])[kk];
      float4 l4 = reinterpret_cast<const float4*>(sL[g])[kk];
      acc[g] += u4.x * wu[0] + u4.y * wu[1] + u4.z * wu[2] + u4.w * wu[3];
      acc[g] += l4.x * wl[0] + l4.y * wl[1] + l4.z * wl[2] + l4.w * wl[3];
    }
  }
  float bu = b_user[d];
  for (int g = 0; g < 8; ++g) q[(g0 + g) * DIM + d] = acc[g] + bu;
}

// ---------------------------------------------------------------------------
// Kernel 2 (fused, wave-per-graph, register-disciplined):
// per 16-node tile of the wave's graph g: e = sigmoid(q[g]+feat@W).w_e via
// swapped-operand MFMA; xor16+32 leaves full e on all lanes; wt=cnt*exp(e)
// (log/exp cancel, no max — bounded, R11-verified); acc += wt*fv in-register.
// q row is WAVE-UNIFORM -> staged in LDS (512B/wave), read as broadcast.
// __launch_bounds__(256,4) caps VGPR at 128 (audited live set ~115, no
// spill — R14's 172-VGPR/45MB-scratch failure mode eliminated).
// feat read EXACTLY once; no seg loads; no skernel; no e buffer.
// ---------------------------------------------------------------------------
__global__ __launch_bounds__(256, 4) void gkernel(
    const float* __restrict__ feat, const unsigned short* __restrict__ Wt,
    const float* __restrict__ w_e, const float* __restrict__ cnt,
    const int* __restrict__ bounds, const float* __restrict__ q,
    float* __restrict__ rst) {
  __shared__ unsigned short sW[128 * DIM];
  __shared__ float sWe[DIM];
  __shared__ float sQ[4][DIM];
  const int tid = threadIdx.x;
  const int l = tid & 63, w = tid >> 6;
  const int lr = l & 15, lh = l >> 4;
  const int g = blockIdx.x * 4 + w;

  const int s0 = bounds[g], s1 = bounds[g + 1];

  // ---- stage q row for this wave (512B, lanes < 32), before the barrier
  if (l < 32)
    reinterpret_cast<float4*>(sQ[w])[l] =
        reinterpret_cast<const float4*>(q)[(size_t)g * 32 + l];

  // ---- stage Wt (XOR-swizzled, R9-proven) + w_e
  const uint4* Wt4 = reinterpret_cast<const uint4*>(Wt);
#pragma unroll
  for (int i = 0; i < 8; ++i) {
    int hw = i * 2048 + tid * 8;
    int row = hw >> 7, k0 = hw & 127;
    uint4 wv = Wt4[i * 256 + tid];
    *reinterpret_cast<uint4*>(&sW[row * DIM + (k0 ^ ((row & 7) << 3))]) = wv;
  }
  if (tid < 32)
    reinterpret_cast<float4*>(sWe)[tid] =
        reinterpret_cast<const float4*>(w_e)[tid];

  __syncthreads();  // only barrier

  if (s1 <= s0) {  // empty graph -> zero row
    if (l < 32)
      reinterpret_cast<float4*>(rst)[(size_t)g * 32 + l] =
          float4{0.f, 0.f, 0.f, 0.f};
    return;
  }

  float4 acc[4][2];
#pragma unroll
  for (int ks = 0; ks < 4; ++ks) {
    acc[ks][0] = float4{0.f, 0.f, 0.f, 0.f};
    acc[ks][1] = float4{0.f, 0.f, 0.f, 0.f};
  }
  float s = 0.0f;

  const int ntiles = (s1 - s0 + 15) >> 4;
  for (int t = 0; t < ntiles; ++t) {
    const int node = s0 + t * 16 + lr;
    const bool valid = node < s1;
    const int nc = valid ? node : (s1 - 1);

    // ---- feat tile (8 float4 burst)
    const float* rp = feat + (size_t)nc * DIM + lh * 8;
    float4 fv[4][2];
#pragma unroll
    for (int ks = 0; ks < 4; ++ks) {
      fv[ks][0] = *reinterpret_cast<const float4*>(rp + ks * 32);
      fv[ks][1] = *reinterpret_cast<const float4*>(rp + ks * 32 + 4);
    }
    const float lc = cnt[nc];

    bf16x8 af[4];
#pragma unroll
    for (int ks = 0; ks < 4; ++ks) {
      union { bf16x8 v; unsigned short u[8]; } a;
      a.u[0] = bfrne(fv[ks][0].x); a.u[1] = bfrne(fv[ks][0].y);
      a.u[2] = bfrne(fv[ks][0].z); a.u[3] = bfrne(fv[ks][0].w);
      a.u[4] = bfrne(fv[ks][1].x); a.u[5] = bfrne(fv[ks][1].y);
      a.u[6] = bfrne(fv[ks][1].z); a.u[7] = bfrne(fv[ks][1].w);
      af[ks] = a.v;
    }

    // ---- e partial: D[keycol = c*16 + 4*lh + r][node = lr]
    float p = 0.0f;
#pragma unroll
    for (int c = 0; c < 8; ++c) {
      const int row = c * 16 + lr;
      bf16x8 wf[4];
#pragma unroll
      for (int ks = 0; ks < 4; ++ks)
        wf[ks] = *reinterpret_cast<const bf16x8*>(
            &sW[row * DIM + ((ks * 32 + lh * 8) ^ ((row & 7) << 3))]);
      float4 we = *reinterpret_cast<const float4*>(&sWe[c * 16 + lh * 4]);
      float4 qc = *reinterpret_cast<const float4*>(&sQ[w][c * 16 + lh * 4]);

      f32x4 a0 = f32x4{0.f, 0.f, 0.f, 0.f};
#pragma unroll
      for (int ks = 0; ks < 4; ++ks)
        a0 = __builtin_amdgcn_mfma_f32_16x16x32_bf16(wf[ks], af[ks], a0, 0, 0, 0);

      p += we.x * sigf(a0[0] + qc.x) + we.y * sigf(a0[1] + qc.y) +
           we.z * sigf(a0[2] + qc.z) + we.w * sigf(a0[3] + qc.w);
    }
    // xor-reduce over lh: ALL lanes end with the full e_pre of node lr
    p += __shfl_xor(p, 16, 64);
    p += __shfl_xor(p, 32, 64);

    // ---- fused softmax weight + weighted feature accumulation
    const float wt = valid ? lc * __expf(p) : 0.0f;
    s += wt;
#pragma unroll
    for (int ks = 0; ks < 4; ++ks) {
      acc[ks][0].x += wt * fv[ks][0].x; acc[ks][0].y += wt * fv[ks][0].y;
      acc[ks][0].z += wt * fv[ks][0].z; acc[ks][0].w += wt * fv[ks][0].w;
      acc[ks][1].x += wt * fv[ks][1].x; acc[ks][1].y += wt * fv[ks][1].y;
      acc[ks][1].z += wt * fv[ks][1].z; acc[ks][1].w += wt * fv[ks][1].w;
    }
  }

  // ---- reduce over the 16 lr lanes (xor 1,2,4,8)
#pragma unroll
  for (int m = 1; m <= 8; m <<= 1) {
    s += __shfl_xor(s, m, 64);
#pragma unroll
    for (int ks = 0; ks < 4; ++ks)
#pragma unroll
      for (int jh = 0; jh < 2; ++jh) {
        acc[ks][jh].x += __shfl_xor(acc[ks][jh].x, m, 64);
        acc[ks][jh].y += __shfl_xor(acc[ks][jh].y, m, 64);
        acc[ks][jh].z += __shfl_xor(acc[ks][jh].z, m, 64);
        acc[ks][jh].w += __shfl_xor(acc[ks][jh].w, m, 64);
      }
  }

  const float inv = 1.0f / s;
  // lane lr in [0,8): writes float4 chunk (ks = lr>>1, jh = lr&1) of its lh
  // block: col = ks*32 + lh*8 + jh*4 -> float4 idx = ks*8 + lh*2 + jh
  if (lr < 8) {
    const int ks = lr >> 1, jh = lr & 1;
    float4 v;
    v.x = acc[ks][jh].x * inv; v.y = acc[ks][jh].y * inv;
    v.z = acc[ks][jh].z * inv; v.w = acc[ks][jh].w * inv;
    reinterpret_cast<float4*>(rst)[(size_t)g * 32 + ks * 8 + lh * 2 + jh] = v;
  }
}

// ---------------------------------------------------------------------------
extern "C" void kernel_launch(void* const* d_in, const int* in_sizes, int n_in,
                              void* d_out, int out_size, void* d_ws,
                              size_t ws_size, hipStream_t stream) {
  const float* feat = (const float*)d_in[0];
  const float* U_feat = (const float*)d_in[1];
  const float* cnt = (const float*)d_in[2];
  const float* W_key = (const float*)d_in[3];
  const float* W_user = (const float*)d_in[4];
  const float* b_user = (const float*)d_in[5];
  const float* W_last = (const float*)d_in[6];
  const float* w_e = (const float*)d_in[7];
  const int* last_nodes = (const int*)d_in[8];
  const int* seg = (const int*)d_in[9];
  float* out = (float*)d_out;

  float* q = (float*)d_ws;                              // 4096*128 f32 (2 MB)
  unsigned short* Wt = (unsigned short*)(q + B_GRAPHS * DIM);  // 32 KB
  int* bounds = (int*)(Wt + DIM * DIM);                 // 4097 ints

  qkernel<<<512 + 64 + N_NODES / 128, 128, 0, stream>>>(
      feat, U_feat, W_user, b_user, W_last, last_nodes, W_key, Wt, seg,
      bounds, q);
  gkernel<<<B_GRAPHS / 4, 256, 0, stream>>>(feat, Wt, w_e, cnt, bounds, q, out);
}

// Round 16
// 202.594 us; speedup vs baseline: 1.1478x; 1.1478x over previous
//
#include <hip/hip_runtime.h>
#include <hip/hip_bf16.h>
#include <math.h>

#define N_NODES 204800
#define B_GRAPHS 4096
#define DIM 128

typedef __attribute__((ext_vector_type(8))) short bf16x8;
typedef __attribute__((ext_vector_type(4))) float f32x4;

__device__ __forceinline__ float sigf(float x) {
    return 1.0f / (1.0f + __expf(-x));
}

__device__ __forceinline__ unsigned short bfrne(float x) {
    unsigned u = __float_as_uint(x);
    unsigned r = u + 0x7FFFu + ((u >> 16) & 1u);
    return (unsigned short)(r >> 16);
}

__device__ __forceinline__ float b2f(unsigned short h) {
    return __uint_as_float((unsigned)h << 16);
}

// ---------------------------------------------------------------------------
// Kernel 1, three jobs by blockIdx.x:
//   [0..512):    q[b] = U_feat[b]@W_user + b_user + feat[last[b]]@W_last
//   [512..576):  Wt_bf16[c][k] = bf16(W_key[k][c])
//   [576..2176): bounds scatter (segments sorted & contiguous)
// ---------------------------------------------------------------------------
__global__ __launch_bounds__(128) void qkernel(
    const float* __restrict__ feat, const float* __restrict__ U_feat,
    const float* __restrict__ W_user, const float* __restrict__ b_user,
    const float* __restrict__ W_last, const int* __restrict__ last_nodes,
    const float* __restrict__ W_key, unsigned short* __restrict__ Wt,
    const int* __restrict__ seg, int* __restrict__ bounds,
    float* __restrict__ q) {
  if (blockIdx.x >= 576) {
    int n = (blockIdx.x - 576) * 128 + threadIdx.x;
    int sc = seg[n];
    int sp = (n == 0) ? -1 : seg[n - 1];
    for (int b = sp + 1; b <= sc; ++b) bounds[b] = (b == 0) ? 0 : n;
    if (n == N_NODES - 1)
      for (int b = sc + 1; b <= B_GRAPHS; ++b) bounds[b] = N_NODES;
    return;
  }
  if (blockIdx.x >= 512) {
    int b = blockIdx.x - 512;  // 0..63
#pragma unroll
    for (int j = 0; j < 2; ++j) {
      int o = b * 256 + j * 128 + threadIdx.x;
      int c = o >> 7, k = o & 127;
      Wt[o] = bfrne(W_key[k * DIM + c]);
    }
    return;
  }
  __shared__ float sU[8][DIM];
  __shared__ float sL[8][DIM];
  const int d = threadIdx.x;
  const int g0 = blockIdx.x * 8;
  for (int g = 0; g < 8; ++g) {
    sU[g][d] = U_feat[(g0 + g) * DIM + d];
    int ln = last_nodes[g0 + g];
    sL[g][d] = feat[ln * DIM + d];
  }
  __syncthreads();
  float acc[8];
#pragma unroll
  for (int g = 0; g < 8; ++g) acc[g] = 0.0f;
  for (int kk = 0; kk < 32; ++kk) {
    float wu[4], wl[4];
#pragma unroll
    for (int j = 0; j < 4; ++j) {
      wu[j] = W_user[(kk * 4 + j) * DIM + d];
      wl[j] = W_last[(kk * 4 + j) * DIM + d];
    }
#pragma unroll
    for (int g = 0; g < 8; ++g) {
      float4 u4 = reinterpret_cast<const float4*>(sU[g])[kk];
      float4 l4 = reinterpret_cast<const float4*>(sL[g])[kk];
      acc[g] += u4.x * wu[0] + u4.y * wu[1] + u4.z * wu[2] + u4.w * wu[3];
      acc[g] += l4.x * wl[0] + l4.y * wl[1] + l4.z * wl[2] + l4.w * wl[3];
    }
  }
  float bu = b_user[d];
  for (int g = 0; g < 8; ++g) q[(g0 + g) * DIM + d] = acc[g] + bu;
}

// ---------------------------------------------------------------------------
// Kernel 2 (fused, wave-per-graph, minimal live set):
// per 16-node tile of graph g: e = sigmoid(q[g]+feat@W).w_e via swapped-
// operand MFMA; xor16+32 leaves e on all lanes; wt = cnt*exp(e) (log/exp
// cancel, no max — bounded, R11-verified); acc += wt * bf16(feat) — the
// weighted sum reuses the bf16 MFMA fragments so the fp32 fv array (32
// VGPR) is NOT kept live (adds <=~0.004 absmax, threshold 0.018).
// q row is wave-uniform -> LDS broadcast (R15-verified correct).
// __launch_bounds__(256,3): caps ~170 regs (audited live ~95), cannot
// trigger the 64-reg spill mode that killed R10/R15.
// ---------------------------------------------------------------------------
__global__ __launch_bounds__(256, 3) void gkernel(
    const float* __restrict__ feat, const unsigned short* __restrict__ Wt,
    const float* __restrict__ w_e, const float* __restrict__ cnt,
    const int* __restrict__ bounds, const float* __restrict__ q,
    float* __restrict__ rst) {
  __shared__ unsigned short sW[128 * DIM];
  __shared__ float sWe[DIM];
  __shared__ float sQ[4][DIM];
  const int tid = threadIdx.x;
  const int l = tid & 63, w = tid >> 6;
  const int lr = l & 15, lh = l >> 4;
  const int g = blockIdx.x * 4 + w;

  const int s0 = bounds[g], s1 = bounds[g + 1];

  // ---- stage q row for this wave (512B, lanes < 32), before the barrier
  if (l < 32)
    reinterpret_cast<float4*>(sQ[w])[l] =
        reinterpret_cast<const float4*>(q)[(size_t)g * 32 + l];

  // ---- stage Wt (XOR-swizzled, R9-proven) + w_e
  const uint4* Wt4 = reinterpret_cast<const uint4*>(Wt);
#pragma unroll
  for (int i = 0; i < 8; ++i) {
    int hw = i * 2048 + tid * 8;
    int row = hw >> 7, k0 = hw & 127;
    uint4 wv = Wt4[i * 256 + tid];
    *reinterpret_cast<uint4*>(&sW[row * DIM + (k0 ^ ((row & 7) << 3))]) = wv;
  }
  if (tid < 32)
    reinterpret_cast<float4*>(sWe)[tid] =
        reinterpret_cast<const float4*>(w_e)[tid];

  __syncthreads();  // only barrier

  if (s1 <= s0) {  // empty graph -> zero row
    if (l < 32)
      reinterpret_cast<float4*>(rst)[(size_t)g * 32 + l] =
          float4{0.f, 0.f, 0.f, 0.f};
    return;
  }

  // acc[ks][jh] covers col = ks*32 + lh*8 + jh*4 (+0..3): 32 cols per lane
  float4 acc[4][2];
#pragma unroll
  for (int ks = 0; ks < 4; ++ks) {
    acc[ks][0] = float4{0.f, 0.f, 0.f, 0.f};
    acc[ks][1] = float4{0.f, 0.f, 0.f, 0.f};
  }
  float s = 0.0f;

  const int ntiles = (s1 - s0 + 15) >> 4;
  for (int t = 0; t < ntiles; ++t) {
    const int node = s0 + t * 16 + lr;
    const bool valid = node < s1;
    const int nc = valid ? node : (s1 - 1);

    // ---- feat tile: 8 float4 burst, converted immediately to bf16 (fv dies)
    const float* rp = feat + (size_t)nc * DIM + lh * 8;
    bf16x8 af[4];
#pragma unroll
    for (int ks = 0; ks < 4; ++ks) {
      float4 v0 = *reinterpret_cast<const float4*>(rp + ks * 32);
      float4 v1 = *reinterpret_cast<const float4*>(rp + ks * 32 + 4);
      union { bf16x8 v; unsigned short u[8]; } a;
      a.u[0] = bfrne(v0.x); a.u[1] = bfrne(v0.y);
      a.u[2] = bfrne(v0.z); a.u[3] = bfrne(v0.w);
      a.u[4] = bfrne(v1.x); a.u[5] = bfrne(v1.y);
      a.u[6] = bfrne(v1.z); a.u[7] = bfrne(v1.w);
      af[ks] = a.v;
    }
    const float lc = cnt[nc];

    // ---- e partial: D[keycol = c*16 + 4*lh + r][node = lr]
    float p = 0.0f;
#pragma unroll
    for (int c = 0; c < 8; ++c) {
      const int row = c * 16 + lr;
      bf16x8 wf[4];
#pragma unroll
      for (int ks = 0; ks < 4; ++ks)
        wf[ks] = *reinterpret_cast<const bf16x8*>(
            &sW[row * DIM + ((ks * 32 + lh * 8) ^ ((row & 7) << 3))]);
      float4 we = *reinterpret_cast<const float4*>(&sWe[c * 16 + lh * 4]);
      float4 qc = *reinterpret_cast<const float4*>(&sQ[w][c * 16 + lh * 4]);

      f32x4 a0 = f32x4{0.f, 0.f, 0.f, 0.f};
#pragma unroll
      for (int ks = 0; ks < 4; ++ks)
        a0 = __builtin_amdgcn_mfma_f32_16x16x32_bf16(wf[ks], af[ks], a0, 0, 0, 0);

      p += we.x * sigf(a0[0] + qc.x) + we.y * sigf(a0[1] + qc.y) +
           we.z * sigf(a0[2] + qc.z) + we.w * sigf(a0[3] + qc.w);
    }
    // xor-reduce over lh: ALL lanes end with the full e_pre of node lr
    p += __shfl_xor(p, 16, 64);
    p += __shfl_xor(p, 32, 64);

    // ---- fused softmax weight + weighted accumulation from bf16 fragments
    const float wt = valid ? lc * __expf(p) : 0.0f;
    s += wt;
#pragma unroll
    for (int ks = 0; ks < 4; ++ks) {
      union { bf16x8 v; unsigned short u[8]; } a;
      a.v = af[ks];
      acc[ks][0].x += wt * b2f(a.u[0]); acc[ks][0].y += wt * b2f(a.u[1]);
      acc[ks][0].z += wt * b2f(a.u[2]); acc[ks][0].w += wt * b2f(a.u[3]);
      acc[ks][1].x += wt * b2f(a.u[4]); acc[ks][1].y += wt * b2f(a.u[5]);
      acc[ks][1].z += wt * b2f(a.u[6]); acc[ks][1].w += wt * b2f(a.u[7]);
    }
  }

  // ---- reduce over the 16 lr lanes (xor 1,2,4,8)
#pragma unroll
  for (int m = 1; m <= 8; m <<= 1) {
    s += __shfl_xor(s, m, 64);
#pragma unroll
    for (int ks = 0; ks < 4; ++ks)
#pragma unroll
      for (int jh = 0; jh < 2; ++jh) {
        acc[ks][jh].x += __shfl_xor(acc[ks][jh].x, m, 64);
        acc[ks][jh].y += __shfl_xor(acc[ks][jh].y, m, 64);
        acc[ks][jh].z += __shfl_xor(acc[ks][jh].z, m, 64);
        acc[ks][jh].w += __shfl_xor(acc[ks][jh].w, m, 64);
      }
  }

  const float inv = 1.0f / s;
  // lane lr in [0,8): writes float4 chunk (ks = lr>>1, jh = lr&1) of its lh
  // block: col = ks*32 + lh*8 + jh*4 -> float4 idx = ks*8 + lh*2 + jh
  if (lr < 8) {
    const int ks = lr >> 1, jh = lr & 1;
    float4 v;
    v.x = acc[ks][jh].x * inv; v.y = acc[ks][jh].y * inv;
    v.z = acc[ks][jh].z * inv; v.w = acc[ks][jh].w * inv;
    reinterpret_cast<float4*>(rst)[(size_t)g * 32 + ks * 8 + lh * 2 + jh] = v;
  }
}

// ---------------------------------------------------------------------------
extern "C" void kernel_launch(void* const* d_in, const int* in_sizes, int n_in,
                              void* d_out, int out_size, void* d_ws,
                              size_t ws_size, hipStream_t stream) {
  const float* feat = (const float*)d_in[0];
  const float* U_feat = (const float*)d_in[1];
  const float* cnt = (const float*)d_in[2];
  const float* W_key = (const float*)d_in[3];
  const float* W_user = (const float*)d_in[4];
  const float* b_user = (const float*)d_in[5];
  const float* W_last = (const float*)d_in[6];
  const float* w_e = (const float*)d_in[7];
  const int* last_nodes = (const int*)d_in[8];
  const int* seg = (const int*)d_in[9];
  float* out = (float*)d_out;

  float* q = (float*)d_ws;                              // 4096*128 f32 (2 MB)
  unsigned short* Wt = (unsigned short*)(q + B_GRAPHS * DIM);  // 32 KB
  int* bounds = (int*)(Wt + DIM * DIM);                 // 4097 ints

  qkernel<<<512 + 64 + N_NODES / 128, 128, 0, stream>>>(
      feat, U_feat, W_user, b_user, W_last, last_nodes, W_key, Wt, seg,
      bounds, q);
  gkernel<<<B_GRAPHS / 4, 256, 0, stream>>>(feat, Wt, w_e, cnt, bounds, q, out);
}

// Round 17
// 64.864 us; speedup vs baseline: 3.5851x; 3.1233x over previous
//
#include <hip/hip_runtime.h>
#include <hip/hip_bf16.h>
#include <math.h>

#define N_NODES 204800
#define B_GRAPHS 4096
#define DIM 128

typedef __attribute__((ext_vector_type(8))) short bf16x8;
typedef __attribute__((ext_vector_type(4))) float f32x4;

__device__ __forceinline__ float sigf(float x) {
    return 1.0f / (1.0f + __expf(-x));
}

__device__ __forceinline__ unsigned short bfrne(float x) {
    unsigned u = __float_as_uint(x);
    unsigned r = u + 0x7FFFu + ((u >> 16) & 1u);
    return (unsigned short)(r >> 16);
}

// ---------------------------------------------------------------------------
// Kernel 1, three jobs by blockIdx.x:
//   [0..512):    q[b] = U_feat[b]@W_user + b_user + feat[last[b]]@W_last
//   [512..576):  Wt_bf16[c][k] = bf16(W_key[k][c])
//   [576..2176): bounds scatter (segments sorted & contiguous)
// ---------------------------------------------------------------------------
__global__ __launch_bounds__(128) void qkernel(
    const float* __restrict__ feat, const float* __restrict__ U_feat,
    const float* __restrict__ W_user, const float* __restrict__ b_user,
    const float* __restrict__ W_last, const int* __restrict__ last_nodes,
    const float* __restrict__ W_key, unsigned short* __restrict__ Wt,
    const int* __restrict__ seg, int* __restrict__ bounds,
    float* __restrict__ q) {
  if (blockIdx.x >= 576) {
    int n = (blockIdx.x - 576) * 128 + threadIdx.x;
    int sc = seg[n];
    int sp = (n == 0) ? -1 : seg[n - 1];
    for (int b = sp + 1; b <= sc; ++b) bounds[b] = (b == 0) ? 0 : n;
    if (n == N_NODES - 1)
      for (int b = sc + 1; b <= B_GRAPHS; ++b) bounds[b] = N_NODES;
    return;
  }
  if (blockIdx.x >= 512) {
    int b = blockIdx.x - 512;  // 0..63
#pragma unroll
    for (int j = 0; j < 2; ++j) {
      int o = b * 256 + j * 128 + threadIdx.x;
      int c = o >> 7, k = o & 127;
      Wt[o] = bfrne(W_key[k * DIM + c]);
    }
    return;
  }
  __shared__ float sU[8][DIM];
  __shared__ float sL[8][DIM];
  const int d = threadIdx.x;
  const int g0 = blockIdx.x * 8;
  for (int g = 0; g < 8; ++g) {
    sU[g][d] = U_feat[(g0 + g) * DIM + d];
    int ln = last_nodes[g0 + g];
    sL[g][d] = feat[ln * DIM + d];
  }
  __syncthreads();
  float acc[8];
#pragma unroll
  for (int g = 0; g < 8; ++g) acc[g] = 0.0f;
  for (int kk = 0; kk < 32; ++kk) {
    float wu[4], wl[4];
#pragma unroll
    for (int j = 0; j < 4; ++j) {
      wu[j] = W_user[(kk * 4 + j) * DIM + d];
      wl[j] = W_last[(kk * 4 + j) * DIM + d];
    }
#pragma unroll
    for (int g = 0; g < 8; ++g) {
      float4 u4 = reinterpret_cast<const float4*>(sU[g])[kk];
      float4 l4 = reinterpret_cast<const float4*>(sL[g])[kk];
      acc[g] += u4.x * wu[0] + u4.y * wu[1] + u4.z * wu[2] + u4.w * wu[3];
      acc[g] += l4.x * wl[0] + l4.y * wl[1] + l4.z * wl[2] + l4.w * wl[3];
    }
  }
  float bu = b_user[d];
  for (int g = 0; g < 8; ++g) q[(g0 + g) * DIM + d] = acc[g] + bu;
}

// ---------------------------------------------------------------------------
// Kernel 2: e[n] = sigmoid(q[seg[n]] + (feat[n] @ W_key)) . w_e + log(cnt[n])
// R9 structure + q-rows staged in LDS: a 128-node block spans only a few
// graphs (nodes sorted by segment), so the block stages rows g0..g0+7 into
// padded sQ (4KB) and the per-c q read becomes an LDS broadcast. This cuts
// the q stream from 105 MB (512B/node from L2) to ~2.4 MB (512B/graph).
// Fallback to the R9 global path if the block spans >8 graphs (essentially
// never: mean segment 50 nodes). Frees the 32 qv VGPRs too.
// Swapped-operand MFMA: D[keycol = c*16 + 4*lh + reg][node = lr].
// ---------------------------------------------------------------------------
__global__ __launch_bounds__(512, 4) void ekernel(
    const float* __restrict__ feat, const unsigned short* __restrict__ Wt,
    const float* __restrict__ w_e, const float* __restrict__ cnt,
    const int* __restrict__ seg, const float* __restrict__ q,
    float* __restrict__ e) {
  __shared__ unsigned short sW[128 * DIM];
  __shared__ float sWe[DIM];
  __shared__ float sQ[8][DIM + 4];  // +4-float pad: breaks idx-aligned banks
  const int tid = threadIdx.x;
  const int base = blockIdx.x * 128;
  const int l = tid & 63, w = tid >> 6;     // 8 waves
  const int lr = l & 15, lh = l >> 4;
  const int node = base + w * 16 + lr;      // this lane's node (lh-replicated)

  // ---- block's graph range (broadcast scalar loads)
  const int g0 = seg[base];
  const int gcnt = seg[base + 127] - g0 + 1;
  const bool fits = (gcnt <= 8);

  // ---- per-lane seg + cnt
  const int sg = seg[node];
  const float lc = cnt[node];

  // ---- batch 8 feat float4 loads (one row per lane, 32B per (lane,ks))
  const float* rp = feat + (size_t)node * DIM + lh * 8;
  float4 fv[4][2];
#pragma unroll
  for (int ks = 0; ks < 4; ++ks) {
    fv[ks][0] = *reinterpret_cast<const float4*>(rp + ks * 32);
    fv[ks][1] = *reinterpret_cast<const float4*>(rp + ks * 32 + 4);
  }

  // ---- stage q rows g0..g0+7 into sQ (threads 0..255, one float4 each)
  const float4* q4p = reinterpret_cast<const float4*>(q);
  if (fits && tid < 256) {
    int row = tid >> 5, ch = tid & 31;
    int gr = g0 + row;
    if (gr < B_GRAPHS) {
      float4 v = q4p[(size_t)gr * 32 + ch];
      *reinterpret_cast<float4*>(&sQ[row][ch * 4]) = v;
    }
  }

  // ---- stage W + w_e into LDS (512 threads: hw = (i*512+tid)*8)
  const uint4* Wt4 = reinterpret_cast<const uint4*>(Wt);
#pragma unroll
  for (int i = 0; i < 4; ++i) {
    int hw = i * 4096 + tid * 8;
    int row = hw >> 7, k0 = hw & 127;
    uint4 wv = Wt4[i * 512 + tid];
    *reinterpret_cast<uint4*>(&sW[row * DIM + (k0 ^ ((row & 7) << 3))]) = wv;
  }
  if (tid < 32)
    reinterpret_cast<float4*>(sWe)[tid] =
        reinterpret_cast<const float4*>(w_e)[tid];

  // ---- cvt feat to bf16 fragments (frees fv)
  bf16x8 af[4];
#pragma unroll
  for (int ks = 0; ks < 4; ++ks) {
    union { bf16x8 v; unsigned short u[8]; } a;
    a.u[0] = bfrne(fv[ks][0].x); a.u[1] = bfrne(fv[ks][0].y);
    a.u[2] = bfrne(fv[ks][0].z); a.u[3] = bfrne(fv[ks][0].w);
    a.u[4] = bfrne(fv[ks][1].x); a.u[5] = bfrne(fv[ks][1].y);
    a.u[6] = bfrne(fv[ks][1].z); a.u[7] = bfrne(fv[ks][1].w);
    af[ks] = a.v;
  }

  __syncthreads();

  const int qidx = sg - g0;  // LDS row for this lane's graph (if fits)

  // ---- c-loop: 8 keycol-tiles of 16
  float p = 0.0f;
#pragma unroll
  for (int c = 0; c < 8; ++c) {
    const int row = c * 16 + lr;
    bf16x8 wf[4];
#pragma unroll
    for (int ks = 0; ks < 4; ++ks)
      wf[ks] = *reinterpret_cast<const bf16x8*>(
          &sW[row * DIM + ((ks * 32 + lh * 8) ^ ((row & 7) << 3))]);
    float4 we = *reinterpret_cast<const float4*>(&sWe[c * 16 + lh * 4]);

    f32x4 a0 = f32x4{0.f, 0.f, 0.f, 0.f};
#pragma unroll
    for (int ks = 0; ks < 4; ++ks)
      a0 = __builtin_amdgcn_mfma_f32_16x16x32_bf16(wf[ks], af[ks], a0, 0, 0, 0);

    float4 qc;
    if (fits)
      qc = *reinterpret_cast<const float4*>(&sQ[qidx][c * 16 + lh * 4]);
    else
      qc = q4p[(size_t)sg * 32 + c * 4 + lh];
    p += we.x * sigf(a0[0] + qc.x) + we.y * sigf(a0[1] + qc.y) +
         we.z * sigf(a0[2] + qc.z) + we.w * sigf(a0[3] + qc.w);
  }

  // reduce over lh (lanes l, l^16, l^32), lh==0 lanes write
  p += __shfl_xor(p, 16, 64);
  p += __shfl_xor(p, 32, 64);
  if (lh == 0) e[node] = p + __logf(lc);
}

// ---------------------------------------------------------------------------
// Kernel 3: wave-per-graph segment softmax + weighted feat sum (no max pass;
// e bounded: |sig-sum| <= ~9, log(cnt) <= 3.9 -> exp(e) <= ~5.4e5, fp32-safe).
// ---------------------------------------------------------------------------
__global__ __launch_bounds__(256) void skernel(
    const float* __restrict__ feat, const int* __restrict__ bounds,
    const float* __restrict__ e, float* __restrict__ rst) {
  const int wave = threadIdx.x >> 6;
  const int lane = threadIdx.x & 63;
  const int g = blockIdx.x * 4 + wave;
  const int s0 = bounds[g], s1 = bounds[g + 1];

  if (s1 <= s0) {
    if (lane < 32)
      reinterpret_cast<float4*>(rst)[(size_t)g * 32 + lane] =
          float4{0.f, 0.f, 0.f, 0.f};
    return;
  }

  float ls = 0.0f;
  for (int i = s0 + lane; i < s1; i += 64) ls += __expf(e[i]);
#pragma unroll
  for (int off = 32; off >= 1; off >>= 1) ls += __shfl_xor(ls, off, 64);
  const float inv = 1.0f / ls;

  const int c = lane & 31;
  const int h = lane >> 5;
  float4 acc = float4{0.f, 0.f, 0.f, 0.f};
  const float4* feat4 = reinterpret_cast<const float4*>(feat);
  for (int n = s0 + h; n < s1; n += 2) {
    float pp = __expf(e[n]);
    float4 f = feat4[(size_t)n * 32 + c];
    acc.x += pp * f.x;
    acc.y += pp * f.y;
    acc.z += pp * f.z;
    acc.w += pp * f.w;
  }
  acc.x += __shfl_xor(acc.x, 32, 64);
  acc.y += __shfl_xor(acc.y, 32, 64);
  acc.z += __shfl_xor(acc.z, 32, 64);
  acc.w += __shfl_xor(acc.w, 32, 64);
  if (h == 0) {
    float4 r;
    r.x = acc.x * inv; r.y = acc.y * inv; r.z = acc.z * inv; r.w = acc.w * inv;
    reinterpret_cast<float4*>(rst)[(size_t)g * 32 + c] = r;
  }
}

// ---------------------------------------------------------------------------
extern "C" void kernel_launch(void* const* d_in, const int* in_sizes, int n_in,
                              void* d_out, int out_size, void* d_ws,
                              size_t ws_size, hipStream_t stream) {
  const float* feat = (const float*)d_in[0];
  const float* U_feat = (const float*)d_in[1];
  const float* cnt = (const float*)d_in[2];
  const float* W_key = (const float*)d_in[3];
  const float* W_user = (const float*)d_in[4];
  const float* b_user = (const float*)d_in[5];
  const float* W_last = (const float*)d_in[6];
  const float* w_e = (const float*)d_in[7];
  const int* last_nodes = (const int*)d_in[8];
  const int* seg = (const int*)d_in[9];
  float* out = (float*)d_out;

  float* q = (float*)d_ws;                       // 4096*128 f32 (2 MB)
  float* e = q + B_GRAPHS * DIM;                 // 204800 f32 (0.82 MB)
  unsigned short* Wt = (unsigned short*)(e + N_NODES);   // 128*128 bf16 (32 KB)
  int* bounds = (int*)(Wt + DIM * DIM);          // 4097 ints

  qkernel<<<512 + 64 + N_NODES / 128, 128, 0, stream>>>(
      feat, U_feat, W_user, b_user, W_last, last_nodes, W_key, Wt, seg,
      bounds, q);
  ekernel<<<N_NODES / 128, 512, 0, stream>>>(feat, Wt, w_e, cnt, seg, q, e);
  skernel<<<B_GRAPHS / 4, 256, 0, stream>>>(feat, bounds, e, out);
}